// Round 4
// baseline (504.581 us; speedup 1.0000x reference)
//
#include <hip/hip_runtime.h>
#include <hip/hip_bf16.h>
#include <math.h>

// ExpertChoiceMoELayer: B=8,S=2048,D=1024,F=2048,E=8 -> T=16384, cap=2048
#define T_TOK 16384
#define DIM   1024
#define FF    2048
#define NE    8
#define CAPK  2048
#define MTE_MAX 16
#define WL1SZ (NE * 8 * MTE_MAX)  // 1024
#define WL2SZ (NE * 4 * MTE_MAX)  // 512

typedef unsigned short u16;
typedef unsigned long long u64;
typedef __attribute__((ext_vector_type(8))) short bf16x8;
typedef __attribute__((ext_vector_type(4))) float f32x4;

__device__ __forceinline__ u16 f2bf(float f) {
  __hip_bfloat16 h = __float2bfloat16(f);
  union { __hip_bfloat16 h; u16 u; } c; c.h = h; return c.u;
}

// fast GELU: 0.5x(1+erf(x/sqrt2)), erf via Abramowitz-Stegun 7.1.26 (|err|<=1.5e-7)
__device__ __forceinline__ float gelu_f(float v) {
  float z = fabsf(v) * 0.70710678118654752f;
  float t = __builtin_amdgcn_rcpf(1.0f + 0.3275911f * z);
  float poly = t * (0.254829592f +
               t * (-0.284496736f +
               t * (1.421413741f +
               t * (-1.453152027f +
               t * 1.061405429f))));
  float ez = __expf(-z * z);
  float erfz = 1.0f - poly * ez;
  erfz = copysignf(erfz, v);
  return 0.5f * v * (1.0f + erfz);
}

__device__ __forceinline__ void async_copy16(const void* g, void* l) {
  __builtin_amdgcn_global_load_lds(
      (const __attribute__((address_space(1))) unsigned int*)g,
      (__attribute__((address_space(3))) unsigned int*)l, 16, 0, 0);
}

// ---- fp32 [E][R][C] -> bf16 [E][C][R] ----
__global__ __launch_bounds__(256) void transpose_cvt(const float* __restrict__ src,
                                                     u16* __restrict__ dst, int R, int C) {
  __shared__ float tile[32][35];
  int e = blockIdx.z;
  int c0 = blockIdx.x * 32, r0 = blockIdx.y * 32;
  const float* s = src + (size_t)e * R * C;
  u16* d = dst + (size_t)e * R * C;
  int tid = threadIdx.x;
#pragma unroll
  for (int i = 0; i < 4; ++i) {
    int idx = tid + i * 256;
    int r = idx >> 5, c = idx & 31;
    tile[r][c] = s[(size_t)(r0 + r) * C + c0 + c];
  }
  __syncthreads();
  int q = tid & 7, cc = tid >> 3;
  ushort4 h;
  h.x = f2bf(tile[q * 4 + 0][cc]);
  h.y = f2bf(tile[q * 4 + 1][cc]);
  h.z = f2bf(tile[q * 4 + 2][cc]);
  h.w = f2bf(tile[q * 4 + 3][cc]);
  *(ushort4*)(d + (size_t)(c0 + cc) * R + r0 + q * 4) = h;
}

// ---- router: fp64-accum logits + softmax; writes probs [T][E] and probsT [E][T] ----
__global__ __launch_bounds__(256) void router_k(const float* __restrict__ x,
                                                const float* __restrict__ Wg,
                                                float* __restrict__ probs,
                                                float* __restrict__ probsT) {
  int tid = threadIdx.x;
  int wid = tid >> 6, lane = tid & 63;
  int t = blockIdx.x * 4 + wid;
  const float* xr = x + (size_t)t * DIM;
  double acc[NE] = {0, 0, 0, 0, 0, 0, 0, 0};
#pragma unroll 1
  for (int it = 0; it < DIM / 64; ++it) {
    int d = it * 64 + lane;
    float xv = xr[d];
    const float4* wrow = (const float4*)(Wg + (size_t)d * NE);
    float4 w0 = wrow[0], w1 = wrow[1];
    acc[0] += (double)xv * (double)w0.x;
    acc[1] += (double)xv * (double)w0.y;
    acc[2] += (double)xv * (double)w0.z;
    acc[3] += (double)xv * (double)w0.w;
    acc[4] += (double)xv * (double)w1.x;
    acc[5] += (double)xv * (double)w1.y;
    acc[6] += (double)xv * (double)w1.z;
    acc[7] += (double)xv * (double)w1.w;
  }
#pragma unroll
  for (int e = 0; e < NE; ++e)
    for (int o = 32; o > 0; o >>= 1) acc[e] += __shfl_down(acc[e], o, 64);
  if (lane == 0) {
    float l[NE], mx = -3.0e38f;
#pragma unroll
    for (int e = 0; e < NE; ++e) { l[e] = (float)acc[e]; mx = fmaxf(mx, l[e]); }
    float s = 0.f;
#pragma unroll
    for (int e = 0; e < NE; ++e) { l[e] = expf(l[e] - mx); s += l[e]; }
    float inv = 1.0f / s;
#pragma unroll
    for (int e = 0; e < NE; ++e) {
      float p = l[e] * inv;
      probs[(size_t)t * NE + e] = p;
      probsT[(size_t)e * T_TOK + t] = p;
    }
  }
}

__global__ __launch_bounds__(256) void init_k(int* cnt, int* cnt2, u64* key) {
  int g = blockIdx.x * 256 + threadIdx.x;
  if (g < NE) { cnt[g] = 0; cnt2[g] = 0; }
  key[g] = 0ull;
}

// ---- per-expert exact top-CAPK: 3-level radix (11/11/10 bits); winners atomicMax key ----
__global__ __launch_bounds__(256) void topk_sel(const float* __restrict__ probsT,
                                                u64* __restrict__ key) {
  __shared__ float pcol[T_TOK];        // 64 KB
  __shared__ unsigned int hist[2048];  // 8 KB
  __shared__ unsigned int chunk[256];
  __shared__ unsigned int bcast[2];
  __shared__ int tcnt[256];
  int e = blockIdx.x, tid = threadIdx.x;
  const float4* src4 = (const float4*)(probsT + (size_t)e * T_TOK);
  for (int i = tid; i < T_TOK / 4; i += 256) ((float4*)pcol)[i] = src4[i];
  unsigned prefix = 0, remaining = CAPK;
#pragma unroll 1
  for (int lvl = 0; lvl < 3; ++lvl) {
    int nb = (lvl == 2) ? 1024 : 2048;
    for (int i = tid; i < 2048; i += 256) hist[i] = 0;
    __syncthreads();
    for (int i = tid; i < T_TOK; i += 256) {
      unsigned k = __float_as_uint(pcol[i]);
      bool m = (lvl == 0) || (lvl == 1 && (k >> 21) == prefix) ||
               (lvl == 2 && (k >> 10) == prefix);
      if (m) {
        unsigned b = (lvl == 0) ? (k >> 21) : (lvl == 1) ? ((k >> 10) & 2047u) : (k & 1023u);
        atomicAdd(&hist[b], 1u);
      }
    }
    __syncthreads();
    int nper = nb / 256;
    unsigned s = 0;
    for (int j = nper - 1; j >= 0; --j) s += hist[tid * nper + j];
    chunk[tid] = s;
    __syncthreads();
    if (tid == 0) {
      unsigned cum = 0;
      int ct = 0;
      for (int t2 = 255; t2 >= 0; --t2) {
        if (cum + chunk[t2] >= remaining) { ct = t2; break; }
        cum += chunk[t2];
      }
      unsigned rem2 = remaining - cum, cum2 = 0;
      for (int j = nper - 1; j >= 0; --j) {
        unsigned h = hist[ct * nper + j];
        if (cum2 + h >= rem2) {
          bcast[0] = (unsigned)(ct * nper + j);
          bcast[1] = rem2 - cum2;
          break;
        }
        cum2 += h;
      }
    }
    __syncthreads();
    unsigned b = bcast[0];
    remaining = bcast[1];
    prefix = (lvl == 0) ? b : (lvl == 1) ? ((prefix << 11) | b) : ((prefix << 10) | b);
    __syncthreads();
  }
  unsigned vk = prefix;
  int need = (int)remaining;
  const int CH = T_TOK / 256;
  int i0 = tid * CH;
  int myt = 0;
  for (int i = i0; i < i0 + CH; ++i)
    myt += (__float_as_uint(pcol[i]) == vk);
  tcnt[tid] = myt;
  __syncthreads();
  if (tid == 0) {
    int r = 0;
    for (int j = 0; j < 256; ++j) { int v = tcnt[j]; tcnt[j] = r; r += v; }
  }
  __syncthreads();
  int run = tcnt[tid];
  u64 ebits = (u64)(7 - e);
  for (int i = i0; i < i0 + CH; ++i) {
    unsigned k = __float_as_uint(pcol[i]);
    bool sv = false;
    if (k > vk) sv = true;
    else if (k == vk) { if (run < need) sv = true; run++; }
    if (sv) atomicMax(&key[i], ((u64)k << 3) | ebits);
  }
}

__global__ __launch_bounds__(256) void assign_k(const float* __restrict__ probs,
                                                const u64* __restrict__ key,
                                                int* __restrict__ tok2exp,
                                                float* __restrict__ wgt, int* cnt) {
  int t = blockIdx.x * 256 + threadIdx.x;
  u64 k = key[t];
  int best;
  float bp;
  if (k) {
    best = 7 - (int)(k & 7);
    bp = __uint_as_float((unsigned)(k >> 3));
  } else {
    best = 0; bp = -3.0e38f;
#pragma unroll
    for (int e = 0; e < NE; ++e) {
      float p = probs[(size_t)t * NE + e];
      if (p > bp) { bp = p; best = e; }
    }
  }
  tok2exp[t] = best;
  wgt[t] = bp;
  atomicAdd(&cnt[best], 1);
}

// basep + XCD-local worklists: entry w -> expert w%8 (block w -> XCD w%8)
__global__ __launch_bounds__(256) void wl_build(const int* __restrict__ cnt,
                                                int* basep, int* wl1, int* wl2) {
  int gid = blockIdx.x * 256 + threadIdx.x;
  int c[NE];
#pragma unroll
  for (int e = 0; e < NE; ++e) c[e] = cnt[e];
  if (gid < NE) {
    int r = 0;
    for (int e = 0; e < gid; ++e) r += c[e];
    basep[gid] = r;
  }
  if (gid < WL1SZ) {
    int e = gid & 7, j = gid >> 3;
    int mte = (c[e] + 255) >> 8;
    int v = -1;
    if (j < 8 * mte) {       // nt half-split: WS = A-panel + 4 B-panels < L2
      int half = 4 * mte;
      int h = (j >= half) ? 1 : 0;
      int jj = j - h * half;
      v = e | ((jj >> 2) << 4) | (((h << 2) | (jj & 3)) << 12);
    }
    wl1[gid] = v;
  }
  int g2 = gid - WL1SZ;
  if (g2 >= 0 && g2 < WL2SZ) {
    int e = g2 & 7, j = g2 >> 3;
    int mte = (c[e] + 255) >> 8;
    int v = -1;
    if (j < 4 * mte) {
      int half = 2 * mte;
      int h = (j >= half) ? 1 : 0;
      int jj = j - h * half;
      v = e | ((jj >> 1) << 4) | (((h << 1) | (jj & 1)) << 12);
    }
    wl2[g2] = v;
  }
}

__global__ __launch_bounds__(256) void slot_k(const int* __restrict__ tok2exp,
                                              const int* __restrict__ basep,
                                              int* cnt2, int* __restrict__ list) {
  int t = blockIdx.x * 256 + threadIdx.x;
  int e = tok2exp[t];
  int s = basep[e] + atomicAdd(&cnt2[e], 1);
  list[s] = t;
}

// ---- gather: Ax[slot][:] = bf16(x[list[slot]][:]) ----
__global__ __launch_bounds__(256) void gather_k(const float* __restrict__ x,
                                                const int* __restrict__ list,
                                                u16* __restrict__ Ax) {
  int wid = threadIdx.x >> 6, lane = threadIdx.x & 63;
  int s0 = blockIdx.x * 16 + wid * 4;
#pragma unroll
  for (int i = 0; i < 4; ++i) {
    int s = s0 + i;
    const float4* src = (const float4*)(x + (size_t)list[s] * DIM);
    ushort4* dst = (ushort4*)(Ax + (size_t)s * DIM);
#pragma unroll
    for (int c = 0; c < DIM / 256; ++c) {
      float4 v = src[lane + c * 64];
      ushort4 h;
      h.x = f2bf(v.x); h.y = f2bf(v.y); h.z = f2bf(v.z); h.w = f2bf(v.w);
      dst[lane + c * 64] = h;
    }
  }
}

// ============ pipelined grouped GEMM: 256x256 tile, BK=64, counted vmcnt, ============
// swizzled LDS, setprio, operand-swapped MFMA, dense A (compacted by slot)
#define MF(M, N_, AV, BV) acc[M][N_] = __builtin_amdgcn_mfma_f32_16x16x32_bf16(BV, AV, acc[M][N_], 0, 0, 0)

#define PHASE_DSA(db, kk, mh)                                                     \
  pa = sm + (((db) * 4 + (kk)) * 16384) + wr * 8192 + (mh) * 4096 + laneOff;      \
  a0 = *(const bf16x8*)(pa);                                                      \
  a1 = *(const bf16x8*)(pa + 1024);                                               \
  a2 = *(const bf16x8*)(pa + 2048);                                               \
  a3 = *(const bf16x8*)(pa + 3072);

#define PHASE_DSB(db, kk)                                                         \
  pb = sm + (((db) * 4 + 2 + (kk)) * 16384) + wc * 4096 + laneOff;                \
  b0 = *(const bf16x8*)(pb);                                                      \
  b1 = *(const bf16x8*)(pb + 1024);                                               \
  b2 = *(const bf16x8*)(pb + 2048);                                               \
  b3 = *(const bf16x8*)(pb + 3072);

#define PHASE_MFMA(mh)                                                            \
  do {                                                                            \
    __builtin_amdgcn_s_setprio(1);                                                \
    MF((mh) * 4 + 0, 0, a0, b0); MF((mh) * 4 + 0, 1, a0, b1);                     \
    MF((mh) * 4 + 0, 2, a0, b2); MF((mh) * 4 + 0, 3, a0, b3);                     \
    MF((mh) * 4 + 1, 0, a1, b0); MF((mh) * 4 + 1, 1, a1, b1);                     \
    MF((mh) * 4 + 1, 2, a1, b2); MF((mh) * 4 + 1, 3, a1, b3);                     \
    MF((mh) * 4 + 2, 0, a2, b0); MF((mh) * 4 + 2, 1, a2, b1);                     \
    MF((mh) * 4 + 2, 2, a2, b2); MF((mh) * 4 + 2, 3, a2, b3);                     \
    MF((mh) * 4 + 3, 0, a3, b0); MF((mh) * 4 + 3, 1, a3, b1);                     \
    MF((mh) * 4 + 3, 2, a3, b2); MF((mh) * 4 + 3, 3, a3, b3);                     \
    __builtin_amdgcn_s_setprio(0);                                                \
  } while (0)

#define STAGE_A(db, kh, kt)                                                        \
  do {                                                                             \
    async_copy16(aP0 + (kt) * 128 + (kh) * 64,                                     \
                 sm + (((db) * 4 + (kh)) * 16384) + wid * 1024);                   \
    async_copy16(aP1 + (kt) * 128 + (kh) * 64,                                     \
                 sm + (((db) * 4 + (kh)) * 16384) + 8192 + wid * 1024);            \
  } while (0)

#define STAGE_B(db, kh, kt)                                                        \
  do {                                                                             \
    async_copy16(bP0 + (kt) * 128 + (kh) * 64,                                     \
                 sm + (((db) * 4 + 2 + (kh)) * 16384) + wid * 1024);               \
    async_copy16(bP1 + (kt) * 128 + (kh) * 64,                                     \
                 sm + (((db) * 4 + 2 + (kh)) * 16384) + 8192 + wid * 1024);        \
  } while (0)

#define BAR() asm volatile("s_barrier" ::: "memory")
#define VM4_BAR() asm volatile("s_waitcnt vmcnt(4)\n\ts_barrier" ::: "memory")
#define VM0_BAR() asm volatile("s_waitcnt vmcnt(0)\n\ts_barrier" ::: "memory")

template <int EPI>
__global__ __launch_bounds__(512, 2) void ffn_k(const u16* __restrict__ A,
                                                const u16* __restrict__ Bm,
                                                void* __restrict__ Out,
                                                const int* __restrict__ list,
                                                const float* __restrict__ wgt,
                                                const int* __restrict__ basep,
                                                const int* __restrict__ cnt,
                                                const int* __restrict__ wl) {
  constexpr int K = EPI ? FF : DIM;
  constexpr int N = EPI ? DIM : FF;
  constexpr int KT = K / 64;

  const int wle = wl[blockIdx.x];
  if (wle < 0) return;
  const int e = wle & 15, mt = (wle >> 4) & 255, nt = wle >> 12;
  const int ce = cnt[e];
  const int be = basep[e];

  __shared__ u16 smem[65536];   // 128 KiB
  __shared__ int toks[256];
  __shared__ float wsc[256];
  char* const sm = (char*)smem;

  const int tid = threadIdx.x;
  if (EPI == 1 && tid < 256) {
    int r = mt * 256 + tid;
    int tk = (r < ce) ? list[be + r] : list[be];
    toks[tid] = tk;
    wsc[tid] = wgt[tk];
  }

  const int wid = tid >> 6, lane = tid & 63;
  const int wr = wid >> 2, wc = wid & 3;
  const int laneOff = ((lane & 15) >> 1) * 128 + (lane & 1) * 64 +
                      (((lane >> 4) << 4) ^ (((lane >> 1) & 3) << 4));

  const int tr0 = tid >> 2, tr1 = 128 + (tid >> 2);
  const int cbl = ((tid & 3) << 4) ^ ((tid & 24) << 1);
  // dense A rows (Ax or H), padded +256 rows past T
  const char* aP0 = (const char*)(A + ((size_t)be + mt * 256 + tr0) * K) + cbl;
  const char* aP1 = (const char*)(A + ((size_t)be + mt * 256 + tr1) * K) + cbl;
  const char* bP0 = (const char*)(Bm + ((size_t)e * N + nt * 256 + tr0) * K) + cbl;
  const char* bP1 = (const char*)(Bm + ((size_t)e * N + nt * 256 + tr1) * K) + cbl;

  f32x4 acc[8][4];
#pragma unroll
  for (int m = 0; m < 8; ++m)
#pragma unroll
    for (int n = 0; n < 4; ++n) acc[m][n] = (f32x4){0.f, 0.f, 0.f, 0.f};

  STAGE_A(0, 0, 0);
  STAGE_B(0, 0, 0);
  STAGE_A(0, 1, 0);
  STAGE_B(0, 1, 0);
  VM4_BAR();

  const char* pa;
  const char* pb;
  bf16x8 a0, a1, a2, a3, b0, b1, b2, b3;

#pragma unroll 1
  for (int t = 0; t < KT - 1; ++t) {
    const int db = t & 1, dn = db ^ 1, kn = t + 1;
    PHASE_DSA(db, 0, 0);
    PHASE_DSB(db, 0);
    STAGE_A(dn, 0, kn);
    BAR();
    PHASE_MFMA(0);
    PHASE_DSA(db, 0, 1);
    STAGE_B(dn, 0, kn);
    VM4_BAR();
    PHASE_MFMA(1);
    PHASE_DSA(db, 1, 0);
    PHASE_DSB(db, 1);
    STAGE_A(dn, 1, kn);
    BAR();
    PHASE_MFMA(0);
    PHASE_DSA(db, 1, 1);
    STAGE_B(dn, 1, kn);
    VM4_BAR();
    PHASE_MFMA(1);
  }
  {
    const int db = (KT - 1) & 1;
    PHASE_DSA(db, 0, 0);
    PHASE_DSB(db, 0);
    BAR();
    PHASE_MFMA(0);
    PHASE_DSA(db, 0, 1);
    VM0_BAR();
    PHASE_MFMA(1);
    PHASE_DSA(db, 1, 0);
    PHASE_DSB(db, 1);
    BAR();
    PHASE_MFMA(0);
    PHASE_DSA(db, 1, 1);
    PHASE_MFMA(1);
  }

  const int lc = lane & 15, lq = (lane >> 4) * 4;
#pragma unroll
  for (int m = 0; m < 8; ++m) {
    int trow = wr * 128 + m * 16 + lc;
    int grow = mt * 256 + trow;
    if (grow < ce) {
      if (EPI == 0) {
        size_t rowoff = (size_t)(be + grow) * FF + nt * 256 + wc * 64 + lq;
#pragma unroll
        for (int n = 0; n < 4; ++n) {
          ushort4 h4;
          h4.x = f2bf(gelu_f(acc[m][n][0]));
          h4.y = f2bf(gelu_f(acc[m][n][1]));
          h4.z = f2bf(gelu_f(acc[m][n][2]));
          h4.w = f2bf(gelu_f(acc[m][n][3]));
          *(ushort4*)((u16*)Out + rowoff + n * 16) = h4;
        }
      } else {
        float w = wsc[trow];
        size_t rowoff = (size_t)toks[trow] * DIM + nt * 256 + wc * 64 + lq;
#pragma unroll
        for (int n = 0; n < 4; ++n) {
          float4 o = make_float4(w * acc[m][n][0], w * acc[m][n][1],
                                 w * acc[m][n][2], w * acc[m][n][3]);
          *(float4*)((float*)Out + rowoff + n * 16) = o;
        }
      }
    }
  }
}

extern "C" void kernel_launch(void* const* d_in, const int* in_sizes, int n_in,
                              void* d_out, int out_size, void* d_ws, size_t ws_size,
                              hipStream_t stream) {
  (void)in_sizes; (void)n_in; (void)out_size; (void)ws_size;
  const float* x  = (const float*)d_in[0];
  const float* Wg = (const float*)d_in[1];
  const float* W1 = (const float*)d_in[2];
  const float* W2 = (const float*)d_in[3];
  float* out = (float*)d_out;

  char* ws = (char*)d_ws;
  size_t off = 0;
  auto alloc = [&](size_t bytes) -> void* {
    void* p = ws + off;
    off += (bytes + 255) & ~(size_t)255;
    return p;
  };
  u16* Ax   = (u16*)alloc((size_t)(T_TOK + 256) * DIM * 2); // 34 MB, padded
  u16* w1t  = (u16*)alloc((size_t)NE * FF * DIM * 2);       // 32 MB  [E][F][D]
  u16* w2t  = (u16*)alloc((size_t)NE * DIM * FF * 2);       // 32 MB  [E][D][F]
  u16* H    = (u16*)alloc((size_t)(T_TOK + 256) * FF * 2);  // 65 MB, padded
  float* probs  = (float*)alloc((size_t)T_TOK * NE * 4);
  float* probsT = (float*)alloc((size_t)NE * T_TOK * 4);
  u64* key      = (u64*)alloc((size_t)T_TOK * 8);
  float* wgt    = (float*)alloc((size_t)T_TOK * 4);
  int* tok2exp  = (int*)alloc((size_t)T_TOK * 4);
  int* list     = (int*)alloc((size_t)T_TOK * 4);
  int* cnt      = (int*)alloc(64);
  int* cnt2     = (int*)alloc(64);
  int* basep    = (int*)alloc(64);
  int* wl1      = (int*)alloc(WL1SZ * 4);
  int* wl2      = (int*)alloc(WL2SZ * 4);

  transpose_cvt<<<dim3(FF / 32, DIM / 32, NE), 256, 0, stream>>>(W1, w1t, DIM, FF);
  transpose_cvt<<<dim3(DIM / 32, FF / 32, NE), 256, 0, stream>>>(W2, w2t, FF, DIM);
  router_k<<<T_TOK / 4, 256, 0, stream>>>(x, Wg, probs, probsT);
  init_k<<<T_TOK / 256, 256, 0, stream>>>(cnt, cnt2, key);
  topk_sel<<<NE, 256, 0, stream>>>(probsT, key);
  assign_k<<<T_TOK / 256, 256, 0, stream>>>(probs, key, tok2exp, wgt, cnt);
  wl_build<<<(WL1SZ + WL2SZ) / 256, 256, 0, stream>>>(cnt, basep, wl1, wl2);
  slot_k<<<T_TOK / 256, 256, 0, stream>>>(tok2exp, basep, cnt2, list);
  gather_k<<<T_TOK / 16, 256, 0, stream>>>(x, list, Ax);
  ffn_k<0><<<WL1SZ, 512, 0, stream>>>(Ax, w1t, H, list, wgt, basep, cnt, wl1);
  ffn_k<1><<<WL2SZ, 512, 0, stream>>>(H, w2t, out, list, wgt, basep, cnt, wl2);
}